// Round 11
// baseline (138.776 us; speedup 1.0000x reference)
//
#include <hip/hip_runtime.h>

#define B_   2
#define N_   16384
#define S_   4096
#define D1_  128
#define D2_  256
#define C1_  256
#define C2_  128
#define M_   (B_ * N_)   // 32768 rows

typedef __bf16 bf16_t;
typedef bf16_t bf16x8 __attribute__((ext_vector_type(8)));
typedef float  f32x4  __attribute__((ext_vector_type(4)));

// ---------------------------------------------------------------- helpers
__device__ __forceinline__ void gload16(const void* g, void* l) {
  __builtin_amdgcn_global_load_lds(
      (const __attribute__((address_space(1))) void*)g,
      (__attribute__((address_space(3))) void*)l, 16, 0, 0);
}

__device__ __forceinline__ float med3a(float a, float b, float c) {
  float d;
  asm("v_med3_f32 %0, %1, %2, %3" : "=v"(d) : "v"(a), "v"(b), "v"(c));
  return d;
}

// candidate payload: (-2x,-2y,-2z,|c|^2), explicit fmaf tree (pass1==pass2 bitwise)
__device__ __forceinline__ float4 cand4(const float* __restrict__ X2, int i) {
  float x = X2[i], y = X2[S_ + i], z = X2[2 * S_ + i];
  float w = fmaf(x, x, fmaf(y, y, z * z));
  return make_float4(-2.f * x, -2.f * y, -2.f * z, w);
}
__device__ __forceinline__ float distv(float4 c, float ax, float ay, float az) {
  return fmaf(ax, c.x, fmaf(ay, c.y, fmaf(az, c.z, c.w)));
}
// value-only top-3 track: fmin + 2x v_med3 (med3(v,m0,m1)==fmin(fmax(v,m0),m1) since m0<=m1)
#define TRACK3(v)                                                        \
  {                                                                      \
    float t0_ = fminf((v), m0);                                          \
    float t1_ = med3a((v), m0, m1);                                      \
    float t2_ = med3a((v), m1, m2);                                      \
    m0 = t0_; m1 = t1_; m2 = t2_;                                        \
  }

// ---------------------------------------------------------------- K0: phase1 — knn + gemmG + points1 transpose + weight prep
// blocks [0,1024): two-pass brute 3-NN -> KW, KI
// blocks [1024,1152): G = p2^T @ W1b -> bf16 [B][4096][256] (128x128 tiles)
// blocks [1152,3200): points1 [B][128][16384] -> Xp1 bf16 [M][128]
// blocks [3200,3328): w1at [256][128], w2t [128][256] bf16
union SMem1 {
  struct { float4 cbuf[1024]; float T3V[2][3][32]; float QMv[32][3]; } knn;
  struct { bf16_t As[128 * 32]; bf16_t Bs[128 * 32]; } gg;
  float tile[2][32][33];
};

__global__ __launch_bounds__(512, 8) void phase1_k(const float* __restrict__ xyz1,
                                                   const float* __restrict__ xyz2,
                                                   const float* __restrict__ points1,
                                                   const float* __restrict__ points2,
                                                   const float* __restrict__ w1,
                                                   const float* __restrict__ w2,
                                                   float* __restrict__ kw,
                                                   int* __restrict__ ki,
                                                   bf16_t* __restrict__ Xp1,
                                                   bf16_t* __restrict__ w1at,
                                                   bf16_t* __restrict__ w2t,
                                                   bf16_t* __restrict__ G) {
  __shared__ SMem1 sm;
  int bi = blockIdx.x, t = threadIdx.x;
  if (bi < 1024) {
    // ---------------- knn (two-pass) ----------------
    int l = t & 63, w = t >> 6;
    int q = l & 31, h = l >> 5;
    int s = w * 2 + h;                          // slice 0..15
    int b  = bi >> 9;                           // 512 blocks per batch
    int nb = (bi & 511) * 32;
    int n  = nb + q;
    const float* X1 = xyz1 + (size_t)b * 3 * N_;
    const float* X2 = xyz2 + (size_t)b * 3 * S_;
    float ax = X1[n], ay = X1[N_ + n], az = X1[2 * N_ + n];
    float p = fmaf(ax, ax, fmaf(ay, ay, az * az));
    float m0 = 3e38f, m1 = 3e38f, m2 = 3e38f;
    // ============ PASS 1: values only ============
    for (int r = 0; r < 4; ++r) {
      __syncthreads();                          // prev round's scan done
      sm.knn.cbuf[t]       = cand4(X2, r * 1024 + t);
      sm.knn.cbuf[t + 512] = cand4(X2, r * 1024 + t + 512);
      __syncthreads();                          // staged data visible
      const float4* cs = sm.knn.cbuf + s * 64;
#pragma unroll 16
      for (int i = 0; i < 64; ++i) {
        float v = distv(cs[i], ax, ay, az);
        TRACK3(v);
      }
    }
    __syncthreads();                            // scans done; reuse cbuf
    float* SV = (float*)sm.knn.cbuf;            // [16][3][32]
    SV[(s * 3 + 0) * 32 + q] = m0;  SV[(s * 3 + 1) * 32 + q] = m1;  SV[(s * 3 + 2) * 32 + q] = m2;
    __syncthreads();
    if (t < 64) {                               // stage A: value-merge 8 slices each
      int th = t >> 5, tq = t & 31;
      float m0 = 3e38f, m1 = 3e38f, m2 = 3e38f;
      for (int s2 = th * 8; s2 < th * 8 + 8; ++s2)
#pragma unroll
        for (int k = 0; k < 3; ++k) {
          float v = SV[(s2 * 3 + k) * 32 + tq];
          TRACK3(v);
        }
      sm.knn.T3V[th][0][tq] = m0; sm.knn.T3V[th][1][tq] = m1; sm.knn.T3V[th][2][tq] = m2;
    }
    __syncthreads();
    float g0 = 3e38f, g1 = 3e38f, g2 = 3e38f;   // query-global top3 (valid on t<32)
    if (t < 32) {
      float m0 = sm.knn.T3V[0][0][t], m1 = sm.knn.T3V[0][1][t], m2 = sm.knn.T3V[0][2][t];
#pragma unroll
      for (int k = 0; k < 3; ++k) {
        float v = sm.knn.T3V[1][k][t];
        TRACK3(v);
      }
      g0 = m0; g1 = m1; g2 = m2;
      sm.knn.QMv[t][0] = m0; sm.knn.QMv[t][1] = m1; sm.knn.QMv[t][2] = m2;
    }
    __syncthreads();
    float q0v = sm.knn.QMv[q][0], q1v = sm.knn.QMv[q][1], q2v = sm.knn.QMv[q][2];
    // ============ PASS 2: index recovery ============
    unsigned j0 = 0xFFFFFFFFu, j1 = 0xFFFFFFFFu, j2 = 0xFFFFFFFFu;
    for (int r = 0; r < 4; ++r) {
      __syncthreads();
      sm.knn.cbuf[t]       = cand4(X2, r * 1024 + t);
      sm.knn.cbuf[t + 512] = cand4(X2, r * 1024 + t + 512);
      __syncthreads();
      const float4* cs = sm.knn.cbuf + s * 64;
      int base = r * 1024 + s * 64;
#pragma unroll
      for (int g = 0; g < 16; ++g) {            // groups of 4
        float v0 = distv(cs[g * 4 + 0], ax, ay, az);
        float v1 = distv(cs[g * 4 + 1], ax, ay, az);
        float v2 = distv(cs[g * 4 + 2], ax, ay, az);
        float v3 = distv(cs[g * 4 + 3], ax, ay, az);
        float gm = fminf(fminf(v0, v1), fminf(v2, v3));
        if (gm <= q2v) {                        // rare
#define CHK(vv, uu)                                                      \
          {                                                              \
            unsigned idx = (unsigned)(base + g * 4 + uu);                \
            bool h0 = ((vv) == q0v) && (j0 == 0xFFFFFFFFu);              \
            bool h1 = ((vv) == q1v) && (j1 == 0xFFFFFFFFu) && !h0;       \
            bool h2 = ((vv) == q2v) && (j2 == 0xFFFFFFFFu) && !h0 && !h1;\
            if (h0) j0 = idx;                                            \
            if (h1) j1 = idx;                                            \
            if (h2) j2 = idx;                                            \
          }
          CHK(v0, 0) CHK(v1, 1) CHK(v2, 2) CHK(v3, 3)
#undef CHK
        }
      }
    }
    __syncthreads();                            // scans done; reuse cbuf
    unsigned* SI = (unsigned*)sm.knn.cbuf;      // [16][3][32]
    SI[(s * 3 + 0) * 32 + q] = j0;  SI[(s * 3 + 1) * 32 + q] = j1;  SI[(s * 3 + 2) * 32 + q] = j2;
    __syncthreads();
    if (t < 32) {                               // min-idx reduce (0xFFFFFFFF = none); t == own query
      unsigned a0 = 0xFFFFFFFFu, a1 = 0xFFFFFFFFu, a2 = 0xFFFFFFFFu;
      for (int s2 = 0; s2 < 16; ++s2) {
        a0 = min(a0, SI[(s2 * 3 + 0) * 32 + t]);
        a1 = min(a1, SI[(s2 * 3 + 1) * 32 + t]);
        a2 = min(a2, SI[(s2 * 3 + 2) * 32 + t]);
      }
      a0 = min(a0, (unsigned)(S_ - 1));
      a1 = min(a1, (unsigned)(S_ - 1));
      a2 = min(a2, (unsigned)(S_ - 1));
      float d0 = fmaxf(p + g0, 1e-6f);
      float d1 = fmaxf(p + g1, 1e-6f);
      float d2 = fmaxf(p + g2, 1e-6f);
      float r0 = 1.f / d0, r1 = 1.f / d1, r2 = 1.f / d2;
      float dn = fmaxf(r0 + r1 + r2, 1e-6f);
      size_t rr = (size_t)b * N_ + n;
      kw[rr * 3 + 0] = r0 / dn;  kw[rr * 3 + 1] = r1 / dn;  kw[rr * 3 + 2] = r2 / dn;
      ki[rr * 3 + 0] = (int)a0;  ki[rr * 3 + 1] = (int)a1;  ki[rr * 3 + 2] = (int)a2;
    }
  } else if (bi < 1152) {
    // ---------------- gemmG: G = p2^T @ W1b, 128x128 tile, K=256 ----------------
    int idx = bi - 1024;
    int bb = idx >> 6, rem = idx & 63;
    int m0 = (rem >> 1) * 128, n0 = (rem & 1) * 128;
    const float* P2 = points2 + (size_t)bb * D2_ * S_;   // [256][4096]
    int lane = t & 63, w = t >> 6;
    int wr = w >> 2, wc = w & 3;                // 2x4 waves; wave tile 64m x 32n
    f32x4 acc[4][2];
    f32x4 z = {0.f, 0.f, 0.f, 0.f};
#pragma unroll
    for (int i = 0; i < 4; ++i) { acc[i][0] = z; acc[i][1] = z; }
    int sA = t & 127, kg = t >> 7;              // 8 k-elems per thread
    for (int k0 = 0; k0 < 256; k0 += 32) {
      __syncthreads();
      {
        bf16x8 ap, bp;
#pragma unroll
        for (int kk = 0; kk < 8; ++kk) {
          ap[kk] = (bf16_t)P2[(size_t)(k0 + kg * 8 + kk) * S_ + m0 + sA];
          bp[kk] = (bf16_t)w1[(size_t)(128 + k0 + kg * 8 + kk) * C1_ + n0 + sA];
        }
        *(bf16x8*)&sm.gg.As[sA * 32 + kg * 8] = ap;
        *(bf16x8*)&sm.gg.Bs[sA * 32 + kg * 8] = bp;
      }
      __syncthreads();
      int arow = wr * 64 + (lane & 15);
      int brow = wc * 32 + (lane & 15);
      int kc = 8 * (lane >> 4);
      bf16x8 bfr[2];
#pragma unroll
      for (int j = 0; j < 2; ++j) bfr[j] = *(const bf16x8*)&sm.gg.Bs[(brow + j * 16) * 32 + kc];
#pragma unroll
      for (int i = 0; i < 4; ++i) {
        bf16x8 af = *(const bf16x8*)&sm.gg.As[(arow + i * 16) * 32 + kc];
#pragma unroll
        for (int j = 0; j < 2; ++j)
          acc[i][j] = __builtin_amdgcn_mfma_f32_16x16x32_bf16(af, bfr[j], acc[i][j], 0, 0, 0);
      }
    }
    bf16_t* Gb = G + (size_t)bb * S_ * 256;
#pragma unroll
    for (int j = 0; j < 2; ++j) {
      int col = n0 + wc * 32 + j * 16 + (lane & 15);
#pragma unroll
      for (int i = 0; i < 4; ++i) {
        int r = m0 + wr * 64 + i * 16 + ((lane >> 4) << 2);
#pragma unroll
        for (int q = 0; q < 4; ++q)
          Gb[(size_t)(r + q) * 256 + col] = (bf16_t)acc[i][j][q];
      }
    }
  } else if (bi < 3200) {
    // ---------------- points1 transpose -> Xp1 [M][128] bf16 ----------------
    int bj = bi - 1152;
    int b = bj >> 10, rest = bj & 1023;
    int n0 = (rest & 255) * 64, c0 = (rest >> 8) * 32;
    int tx = t & 31, ty = (t >> 5) & 7, th = t >> 8;   // th: which 32-n subtile
    const float* src = points1 + (size_t)b * D1_ * N_;
#pragma unroll
    for (int k = 0; k < 4; ++k)
      sm.tile[th][ty + k * 8][tx] = src[(size_t)(c0 + ty + k * 8) * N_ + n0 + th * 32 + tx];
    __syncthreads();
#pragma unroll
    for (int k = 0; k < 4; ++k)
      Xp1[(size_t)(b * N_ + n0 + th * 32 + ty + k * 8) * 128 + c0 + tx] =
          (bf16_t)sm.tile[th][tx][ty + k * 8];
  } else {
    // ---------------- weight prep ----------------
    int i = (bi - 3200) * 512 + t;              // 0 .. 65535
    if (i < 32768) {                            // w1at[n][k] = w1[k][n], k<128
      int n = i >> 7, k = i & 127;
      w1at[i] = (bf16_t)w1[(size_t)k * C1_ + n];
    } else {
      int j = i - 32768;                        // w2t[n][k] = w2[k][n]
      int n = j >> 8, k = j & 255;
      w2t[j] = (bf16_t)w2[(size_t)k * C2_ + n];
    }
  }
}

// ---------------------------------------------------------------- K1: GEMM1 [32768x128]@[128x256] + b1 + Sum w_j G[i_j] -> y1 bf16, BN stats
__global__ __launch_bounds__(256) void gemm1_k(const bf16_t* __restrict__ A,
                                               const bf16_t* __restrict__ Bt,
                                               const float* __restrict__ bias,
                                               const bf16_t* __restrict__ G,
                                               const float* __restrict__ KW,
                                               const int* __restrict__ KI,
                                               bf16_t* __restrict__ Y,
                                               float* __restrict__ st) {
  const int K = 128;
  __shared__ bf16_t As[128 * 32];
  __shared__ bf16_t Bs[128 * 32];
  int tid = threadIdx.x, lane = tid & 63, w = tid >> 6;
  int wr = w >> 1, wc = w & 1;
  int m0 = blockIdx.x * 128, n0 = blockIdx.y * 128;
  int e0 = (w * 2 + 0) * 512 + lane * 8;
  int e1 = (w * 2 + 1) * 512 + lane * 8;
  int ra0 = e0 >> 5, ca0 = e0 & 31;
  int ra1 = e1 >> 5, ca1 = e1 & 31;
  f32x4 acc[4][4];
  f32x4 z = {0.f, 0.f, 0.f, 0.f};
#pragma unroll
  for (int i = 0; i < 4; ++i)
#pragma unroll
    for (int j = 0; j < 4; ++j) acc[i][j] = z;
  for (int k0 = 0; k0 < K; k0 += 32) {
    __syncthreads();
    gload16(A + (size_t)(m0 + ra0) * K + k0 + ca0, &As[e0]);
    gload16(A + (size_t)(m0 + ra1) * K + k0 + ca1, &As[e1]);
    gload16(Bt + (size_t)(n0 + ra0) * K + k0 + ca0, &Bs[e0]);
    gload16(Bt + (size_t)(n0 + ra1) * K + k0 + ca1, &Bs[e1]);
    __syncthreads();
    bf16x8 af[4], bfr[4];
    int arow = wr * 64 + (lane & 15);
    int brow = wc * 64 + (lane & 15);
    int kc = 8 * (lane >> 4);
#pragma unroll
    for (int i = 0; i < 4; ++i) af[i]  = *(const bf16x8*)&As[(arow + i * 16) * 32 + kc];
#pragma unroll
    for (int j = 0; j < 4; ++j) bfr[j] = *(const bf16x8*)&Bs[(brow + j * 16) * 32 + kc];
#pragma unroll
    for (int i = 0; i < 4; ++i)
#pragma unroll
      for (int j = 0; j < 4; ++j)
        acc[i][j] = __builtin_amdgcn_mfma_f32_16x16x32_bf16(af[i], bfr[j], acc[i][j], 0, 0, 0);
  }
  // stage this block's KW/KI into LDS (reuse As)
  __syncthreads();
  float* kwls = (float*)As;                   // 128*3 floats
  int*   kils = ((int*)As) + 384;             // 128*3 ints
  if (tid < 128) {
    int r = m0 + tid;
    kwls[tid * 3 + 0] = KW[(size_t)r * 3 + 0];
    kwls[tid * 3 + 1] = KW[(size_t)r * 3 + 1];
    kwls[tid * 3 + 2] = KW[(size_t)r * 3 + 2];
    kils[tid * 3 + 0] = KI[(size_t)r * 3 + 0];
    kils[tid * 3 + 1] = KI[(size_t)r * 3 + 1];
    kils[tid * 3 + 2] = KI[(size_t)r * 3 + 2];
  }
  __syncthreads();
  int bb = m0 >> 14;
  const bf16_t* Gb = G + (size_t)bb * S_ * 256;
  float sjv[4]  = {0.f, 0.f, 0.f, 0.f};
  float ssjv[4] = {0.f, 0.f, 0.f, 0.f};
#pragma unroll
  for (int i = 0; i < 4; ++i) {
#pragma unroll
    for (int qq = 0; qq < 4; ++qq) {
      int rl = wr * 64 + i * 16 + ((lane >> 4) << 2) + qq;
      float w0 = kwls[rl * 3 + 0], w1v = kwls[rl * 3 + 1], w2v = kwls[rl * 3 + 2];
      const bf16_t* g0 = Gb + (size_t)kils[rl * 3 + 0] * 256;
      const bf16_t* g1 = Gb + (size_t)kils[rl * 3 + 1] * 256;
      const bf16_t* g2 = Gb + (size_t)kils[rl * 3 + 2] * 256;
      int r = m0 + rl;
#pragma unroll
      for (int j = 0; j < 4; ++j) {
        int col = n0 + wc * 64 + j * 16 + (lane & 15);
        float y = acc[i][j][qq] + bias[col]
                + w0 * (float)g0[col] + w1v * (float)g1[col] + w2v * (float)g2[col];
        Y[(size_t)r * C1_ + col] = (bf16_t)y;
        sjv[j] += y;  ssjv[j] += y * y;
      }
    }
  }
#pragma unroll
  for (int j = 0; j < 4; ++j) {
    float sj = sjv[j], ssj = ssjv[j];
    sj  += __shfl_xor(sj, 16);  sj  += __shfl_xor(sj, 32);
    ssj += __shfl_xor(ssj, 16); ssj += __shfl_xor(ssj, 32);
    if ((lane >> 4) == 0) {
      int col = n0 + wc * 64 + j * 16 + (lane & 15);
      atomicAdd(&st[col], sj);
      atomicAdd(&st[C1_ + col], ssj);
    }
  }
}

// ---------------------------------------------------------------- K2: GEMM2 BM=64 (512 blocks) with fused BN1(A-load, prefetched) -> raw y2 transposed + BN2 stats
__global__ __launch_bounds__(256, 3) void gemm2_k(const bf16_t* __restrict__ Y1,
                                                  const bf16_t* __restrict__ Bt,
                                                  const float* __restrict__ bias,
                                                  const float* __restrict__ st1,
                                                  const float* __restrict__ g1v,
                                                  const float* __restrict__ be1,
                                                  float* __restrict__ OUT,
                                                  float* __restrict__ st2) {
  const int K = 256;
  __shared__ bf16_t As[64 * 32];                // 4KB
  __shared__ bf16_t Bs[128 * 32];               // 8KB
  __shared__ float sa1[C1_], sb1[C1_];
  int tid = threadIdx.x, lane = tid & 63, w = tid >> 6;
  int wr = w >> 1, wc = w & 1;                  // 2x2 waves; wave tile 32m x 64n
  int m0 = blockIdx.x * 64;
  {                                             // BN1 coefficients
    const float invM = 1.f / (float)M_;
    float mu  = st1[tid] * invM;
    float var = fmaxf(st1[C1_ + tid] * invM - mu * mu, 0.f);
    float a = g1v[tid] * rsqrtf(var + 1e-5f);
    sa1[tid] = a;
    sb1[tid] = be1[tid] - mu * a;
  }
  int ra = tid >> 2, ca = (tid & 3) * 8;        // A: 64 rows x 32k, 8 elems/thread
  int rb0 = tid >> 2, rb1 = 64 + rb0;           // B: 128 rows, two gload16/thread
  f32x4 acc[2][4];
  f32x4 z = {0.f, 0.f, 0.f, 0.f};
#pragma unroll
  for (int i = 0; i < 2; ++i)
#pragma unroll
    for (int j = 0; j < 4; ++j) acc[i][j] = z;
  bf16x8 va = *(const bf16x8*)&Y1[(size_t)(m0 + ra) * C1_ + ca];
  __syncthreads();                              // sa1/sb1 ready
  for (int k0 = 0; k0 < K; k0 += 32) {
    bf16x8 nv;
    if (k0 + 32 < K)                            // 1-deep prefetch
      nv = *(const bf16x8*)&Y1[(size_t)(m0 + ra) * C1_ + k0 + 32 + ca];
    if (k0) __syncthreads();
    bf16x8 oa;
#pragma unroll
    for (int u = 0; u < 8; ++u) {
      float f0 = (float)va[u];
      f0 = fmaxf(f0 * sa1[k0 + ca + u] + sb1[k0 + ca + u], 0.f);
      oa[u] = (bf16_t)f0;
    }
    *(bf16x8*)&As[ra * 32 + ca] = oa;
    gload16(Bt + (size_t)rb0 * K + k0 + ca, &Bs[rb0 * 32 + ca]);
    gload16(Bt + (size_t)rb1 * K + k0 + ca, &Bs[rb1 * 32 + ca]);
    __syncthreads();
    bf16x8 af[2], bfr[4];
    int arow = wr * 32 + (lane & 15);
    int brow = wc * 64 + (lane & 15);
    int kc = 8 * (lane >> 4);
#pragma unroll
    for (int i = 0; i < 2; ++i) af[i]  = *(const bf16x8*)&As[(arow + i * 16) * 32 + kc];
#pragma unroll
    for (int j = 0; j < 4; ++j) bfr[j] = *(const bf16x8*)&Bs[(brow + j * 16) * 32 + kc];
#pragma unroll
    for (int i = 0; i < 2; ++i)
#pragma unroll
      for (int j = 0; j < 4; ++j)
        acc[i][j] = __builtin_amdgcn_mfma_f32_16x16x32_bf16(af[i], bfr[j], acc[i][j], 0, 0, 0);
    va = nv;
  }
#pragma unroll
  for (int j = 0; j < 4; ++j) {
    int col = wc * 64 + j * 16 + (lane & 15);
    float bv = bias[col];
    float sj = 0.f, ssj = 0.f;
#pragma unroll
    for (int i = 0; i < 2; ++i) {
      int r  = m0 + wr * 32 + i * 16 + ((lane >> 4) << 2);
      int bb = r >> 14, n = r & (N_ - 1);
      f32x4 v = acc[i][j];
#pragma unroll
      for (int q = 0; q < 4; ++q) {
        v[q] += bv;
        sj += v[q]; ssj += v[q] * v[q];
      }
      *(f32x4*)&OUT[((size_t)(bb * C2_ + col)) * N_ + n] = v;
    }
    sj  += __shfl_xor(sj, 16);  sj  += __shfl_xor(sj, 32);
    ssj += __shfl_xor(ssj, 16); ssj += __shfl_xor(ssj, 32);
    if ((lane >> 4) == 0) {
      atomicAdd(&st2[col], sj);
      atomicAdd(&st2[C2_ + col], ssj);
    }
  }
}

// ---------------------------------------------------------------- K3: in-place BN2+ReLU on d_out (BN finalize folded in)
__global__ __launch_bounds__(256) void bn2apply_k(float* __restrict__ OUT,
                                                  const float* __restrict__ st,
                                                  const float* __restrict__ g,
                                                  const float* __restrict__ be) {
  __shared__ float ab[2];
  int t = threadIdx.x;
  int c = (blockIdx.x >> 4) & 127;             // 16 blocks per (b,c) row
  if (t == 0) {
    const float invM = 1.f / (float)M_;
    float mu  = st[c] * invM;
    float var = fmaxf(st[C2_ + c] * invM - mu * mu, 0.f);
    float a = g[c] * rsqrtf(var + 1e-5f);
    ab[0] = a;
    ab[1] = be[c] - mu * a;
  }
  __syncthreads();
  float a = ab[0], s = ab[1];
  size_t i4 = (size_t)blockIdx.x * 256 + t;    // float4 index
  f32x4 v = *(f32x4*)&OUT[i4 * 4];
#pragma unroll
  for (int u = 0; u < 4; ++u) v[u] = fmaxf(a * v[u] + s, 0.f);
  *(f32x4*)&OUT[i4 * 4] = v;
}

// ---------------------------------------------------------------- launch
extern "C" void kernel_launch(void* const* d_in, const int* in_sizes, int n_in,
                              void* d_out, int out_size, void* d_ws, size_t ws_size,
                              hipStream_t stream) {
  const float* xyz1    = (const float*)d_in[0];
  const float* xyz2    = (const float*)d_in[1];
  const float* points1 = (const float*)d_in[2];
  const float* points2 = (const float*)d_in[3];
  const float* w1      = (const float*)d_in[4];
  const float* b1      = (const float*)d_in[5];
  const float* g1      = (const float*)d_in[6];
  const float* beta1   = (const float*)d_in[7];
  const float* w2      = (const float*)d_in[8];
  const float* b2      = (const float*)d_in[9];
  const float* g2      = (const float*)d_in[10];
  const float* beta2   = (const float*)d_in[11];
  float* out = (float*)d_out;

  char* p = (char*)d_ws;
  size_t off = 0;
  bf16_t* Xp1  = (bf16_t*)(p + off); off += (size_t)M_ * 128 * 2;        // 8 MB
  bf16_t* W1AT = (bf16_t*)(p + off); off += (size_t)C1_ * 128 * 2;       // 64 KB
  bf16_t* W2T  = (bf16_t*)(p + off); off += (size_t)C2_ * C1_ * 2;       // 64 KB
  bf16_t* G    = (bf16_t*)(p + off); off += (size_t)B_ * S_ * 256 * 2;   // 4 MB
  bf16_t* Y1   = (bf16_t*)(p + off); off += (size_t)M_ * C1_ * 2;        // 16 MB
  float*  KW   = (float*)(p + off);  off += (size_t)M_ * 3 * 4;          // 384 KB
  int*    KI   = (int*)(p + off);    off += (size_t)M_ * 3 * 4;          // 384 KB
  float*  ST1  = (float*)(p + off);  off += 2048;
  float*  ST2  = (float*)(p + off);  off += 1024;

  hipMemsetAsync(ST1, 0, 3072, stream);   // ST1 + ST2 contiguous

  phase1_k<<<3328, 512, 0, stream>>>(xyz1, xyz2, points1, points2, w1, w2,
                                     KW, KI, Xp1, W1AT, W2T, G);
  gemm1_k<<<dim3(M_ / 128, 2), 256, 0, stream>>>(Xp1, W1AT, b1, G, KW, KI, Y1, ST1);
  gemm2_k<<<M_ / 64, 256, 0, stream>>>(Y1, W2T, b2, ST1, g1, beta1, out, ST2);
  bn2apply_k<<<4096, 256, 0, stream>>>(out, ST2, g2, beta2);
}

// Round 12
// 129.807 us; speedup vs baseline: 1.0691x; 1.0691x over previous
//
#include <hip/hip_runtime.h>

#define B_   2
#define N_   16384
#define S_   4096
#define D1_  128
#define D2_  256
#define C1_  256
#define C2_  128
#define M_   (B_ * N_)   // 32768 rows

typedef __bf16 bf16_t;
typedef bf16_t bf16x8 __attribute__((ext_vector_type(8)));
typedef float  f32x4  __attribute__((ext_vector_type(4)));

// ---------------------------------------------------------------- helpers
__device__ __forceinline__ void gload16(const void* g, void* l) {
  __builtin_amdgcn_global_load_lds(
      (const __attribute__((address_space(1))) void*)g,
      (__attribute__((address_space(3))) void*)l, 16, 0, 0);
}

__device__ __forceinline__ float med3a(float a, float b, float c) {
  float d;
  asm("v_med3_f32 %0, %1, %2, %3" : "=v"(d) : "v"(a), "v"(b), "v"(c));
  return d;
}

// candidate payload: (-2x,-2y,-2z,|c|^2), explicit fmaf tree (pass1==pass2 bitwise)
__device__ __forceinline__ float4 cand4(const float* __restrict__ X2, int i) {
  float x = X2[i], y = X2[S_ + i], z = X2[2 * S_ + i];
  float w = fmaf(x, x, fmaf(y, y, z * z));
  return make_float4(-2.f * x, -2.f * y, -2.f * z, w);
}
__device__ __forceinline__ float distv(float4 c, float ax, float ay, float az) {
  return fmaf(ax, c.x, fmaf(ay, c.y, fmaf(az, c.z, c.w)));
}
// value-only top-3 track: fmin + 2x v_med3 (med3(v,m0,m1)==fmin(fmax(v,m0),m1) since m0<=m1)
#define TRACK3(v)                                                        \
  {                                                                      \
    float t0_ = fminf((v), m0);                                          \
    float t1_ = med3a((v), m0, m1);                                      \
    float t2_ = med3a((v), m1, m2);                                      \
    m0 = t0_; m1 = t1_; m2 = t2_;                                        \
  }

// ---------------------------------------------------------------- K0: phase1 — knn + points1 transpose + weight prep (heterogeneous blocks)
// blocks [0,1024): two-pass brute 3-NN -> KW, KI
// blocks [1024,3072): points1 [B][128][16384] -> Xp1 bf16 [M][128]
// blocks [3072,3200): w1at [256][128], w2t [128][256] bf16
union SMem1 {
  struct { float4 cbuf[1024]; float T3V[2][3][32]; float QMv[32][3]; } knn;
  float tile[2][32][33];
};

__global__ __launch_bounds__(512, 8) void phase1_k(const float* __restrict__ xyz1,
                                                   const float* __restrict__ xyz2,
                                                   const float* __restrict__ points1,
                                                   const float* __restrict__ w1,
                                                   const float* __restrict__ w2,
                                                   float* __restrict__ kw,
                                                   int* __restrict__ ki,
                                                   bf16_t* __restrict__ Xp1,
                                                   bf16_t* __restrict__ w1at,
                                                   bf16_t* __restrict__ w2t) {
  __shared__ SMem1 sm;
  int bi = blockIdx.x, t = threadIdx.x;
  if (bi < 1024) {
    // ---------------- knn (two-pass) ----------------
    int l = t & 63, w = t >> 6;
    int q = l & 31, h = l >> 5;
    int s = w * 2 + h;                          // slice 0..15
    int b  = bi >> 9;                           // 512 blocks per batch
    int nb = (bi & 511) * 32;
    int n  = nb + q;
    const float* X1 = xyz1 + (size_t)b * 3 * N_;
    const float* X2 = xyz2 + (size_t)b * 3 * S_;
    float ax = X1[n], ay = X1[N_ + n], az = X1[2 * N_ + n];
    float p = fmaf(ax, ax, fmaf(ay, ay, az * az));
    float m0 = 3e38f, m1 = 3e38f, m2 = 3e38f;
    // ============ PASS 1: values only ============
    for (int r = 0; r < 4; ++r) {
      __syncthreads();                          // prev round's scan done
      sm.knn.cbuf[t]       = cand4(X2, r * 1024 + t);
      sm.knn.cbuf[t + 512] = cand4(X2, r * 1024 + t + 512);
      __syncthreads();                          // staged data visible
      const float4* cs = sm.knn.cbuf + s * 64;
#pragma unroll 16
      for (int i = 0; i < 64; ++i) {
        float v = distv(cs[i], ax, ay, az);
        TRACK3(v);
      }
    }
    __syncthreads();                            // scans done; reuse cbuf
    float* SV = (float*)sm.knn.cbuf;            // [16][3][32]
    SV[(s * 3 + 0) * 32 + q] = m0;  SV[(s * 3 + 1) * 32 + q] = m1;  SV[(s * 3 + 2) * 32 + q] = m2;
    __syncthreads();
    if (t < 64) {                               // stage A: value-merge 8 slices each
      int th = t >> 5, tq = t & 31;
      float m0 = 3e38f, m1 = 3e38f, m2 = 3e38f;
      for (int s2 = th * 8; s2 < th * 8 + 8; ++s2)
#pragma unroll
        for (int k = 0; k < 3; ++k) {
          float v = SV[(s2 * 3 + k) * 32 + tq];
          TRACK3(v);
        }
      sm.knn.T3V[th][0][tq] = m0; sm.knn.T3V[th][1][tq] = m1; sm.knn.T3V[th][2][tq] = m2;
    }
    __syncthreads();
    float g0 = 3e38f, g1 = 3e38f, g2 = 3e38f;   // query-global top3 (valid on t<32)
    if (t < 32) {
      float m0 = sm.knn.T3V[0][0][t], m1 = sm.knn.T3V[0][1][t], m2 = sm.knn.T3V[0][2][t];
#pragma unroll
      for (int k = 0; k < 3; ++k) {
        float v = sm.knn.T3V[1][k][t];
        TRACK3(v);
      }
      g0 = m0; g1 = m1; g2 = m2;
      sm.knn.QMv[t][0] = m0; sm.knn.QMv[t][1] = m1; sm.knn.QMv[t][2] = m2;
    }
    __syncthreads();
    float q0v = sm.knn.QMv[q][0], q1v = sm.knn.QMv[q][1], q2v = sm.knn.QMv[q][2];
    // ============ PASS 2: index recovery ============
    unsigned j0 = 0xFFFFFFFFu, j1 = 0xFFFFFFFFu, j2 = 0xFFFFFFFFu;
    for (int r = 0; r < 4; ++r) {
      __syncthreads();
      sm.knn.cbuf[t]       = cand4(X2, r * 1024 + t);
      sm.knn.cbuf[t + 512] = cand4(X2, r * 1024 + t + 512);
      __syncthreads();
      const float4* cs = sm.knn.cbuf + s * 64;
      int base = r * 1024 + s * 64;
#pragma unroll
      for (int g = 0; g < 16; ++g) {            // groups of 4
        float v0 = distv(cs[g * 4 + 0], ax, ay, az);
        float v1 = distv(cs[g * 4 + 1], ax, ay, az);
        float v2 = distv(cs[g * 4 + 2], ax, ay, az);
        float v3 = distv(cs[g * 4 + 3], ax, ay, az);
        float gm = fminf(fminf(v0, v1), fminf(v2, v3));
        if (gm <= q2v) {                        // rare
#define CHK(vv, uu)                                                      \
          {                                                              \
            unsigned idx = (unsigned)(base + g * 4 + uu);                \
            bool h0 = ((vv) == q0v) && (j0 == 0xFFFFFFFFu);              \
            bool h1 = ((vv) == q1v) && (j1 == 0xFFFFFFFFu) && !h0;       \
            bool h2 = ((vv) == q2v) && (j2 == 0xFFFFFFFFu) && !h0 && !h1;\
            if (h0) j0 = idx;                                            \
            if (h1) j1 = idx;                                            \
            if (h2) j2 = idx;                                            \
          }
          CHK(v0, 0) CHK(v1, 1) CHK(v2, 2) CHK(v3, 3)
#undef CHK
        }
      }
    }
    __syncthreads();                            // scans done; reuse cbuf
    unsigned* SI = (unsigned*)sm.knn.cbuf;      // [16][3][32]
    SI[(s * 3 + 0) * 32 + q] = j0;  SI[(s * 3 + 1) * 32 + q] = j1;  SI[(s * 3 + 2) * 32 + q] = j2;
    __syncthreads();
    if (t < 32) {                               // min-idx reduce (0xFFFFFFFF = none); t == own query
      unsigned a0 = 0xFFFFFFFFu, a1 = 0xFFFFFFFFu, a2 = 0xFFFFFFFFu;
      for (int s2 = 0; s2 < 16; ++s2) {
        a0 = min(a0, SI[(s2 * 3 + 0) * 32 + t]);
        a1 = min(a1, SI[(s2 * 3 + 1) * 32 + t]);
        a2 = min(a2, SI[(s2 * 3 + 2) * 32 + t]);
      }
      a0 = min(a0, (unsigned)(S_ - 1));
      a1 = min(a1, (unsigned)(S_ - 1));
      a2 = min(a2, (unsigned)(S_ - 1));
      float d0 = fmaxf(p + g0, 1e-6f);
      float d1 = fmaxf(p + g1, 1e-6f);
      float d2 = fmaxf(p + g2, 1e-6f);
      float r0 = 1.f / d0, r1 = 1.f / d1, r2 = 1.f / d2;
      float dn = fmaxf(r0 + r1 + r2, 1e-6f);
      size_t rr = (size_t)b * N_ + n;
      kw[rr * 3 + 0] = r0 / dn;  kw[rr * 3 + 1] = r1 / dn;  kw[rr * 3 + 2] = r2 / dn;
      ki[rr * 3 + 0] = (int)a0;  ki[rr * 3 + 1] = (int)a1;  ki[rr * 3 + 2] = (int)a2;
    }
  } else if (bi < 3072) {
    // ---------------- points1 transpose -> Xp1 [M][128] bf16 ----------------
    int bj = bi - 1024;
    int b = bj >> 10, rest = bj & 1023;
    int n0 = (rest & 255) * 64, c0 = (rest >> 8) * 32;
    int tx = t & 31, ty = (t >> 5) & 7, th = t >> 8;   // th: which 32-n subtile
    const float* src = points1 + (size_t)b * D1_ * N_;
#pragma unroll
    for (int k = 0; k < 4; ++k)
      sm.tile[th][ty + k * 8][tx] = src[(size_t)(c0 + ty + k * 8) * N_ + n0 + th * 32 + tx];
    __syncthreads();
#pragma unroll
    for (int k = 0; k < 4; ++k)
      Xp1[(size_t)(b * N_ + n0 + th * 32 + ty + k * 8) * 128 + c0 + tx] =
          (bf16_t)sm.tile[th][tx][ty + k * 8];
  } else {
    // ---------------- weight prep ----------------
    int i = (bi - 3072) * 512 + t;              // 0 .. 65535
    if (i < 32768) {                            // w1at[n][k] = w1[k][n], k<128
      int n = i >> 7, k = i & 127;
      w1at[i] = (bf16_t)w1[(size_t)k * C1_ + n];
    } else {
      int j = i - 32768;                        // w2t[n][k] = w2[k][n]
      int n = j >> 8, k = j & 255;
      w2t[j] = (bf16_t)w2[(size_t)k * C2_ + n];
    }
  }
}

// ---------------------------------------------------------------- K1: G = p2^T @ W1b -> bf16 [B][4096][256], self-staged transposes (LDP=40, conflict-free)
__global__ __launch_bounds__(512) void gemmG_k(const float* __restrict__ points2,
                                               const float* __restrict__ w1,
                                               bf16_t* __restrict__ G) {
  const int LDP = 40;                           // padded row (elems); 80B, 16B-aligned
  __shared__ bf16_t As[128 * LDP];              // [s][k]
  __shared__ bf16_t Bs[256 * LDP];              // [n][k]
  int t = threadIdx.x, lane = t & 63, w = t >> 6;
  int wr = w >> 2, wc = w & 3;                  // 2x4 waves -> 128m x 256n
  int bb = blockIdx.x >> 5;
  int m0 = (blockIdx.x & 31) * 128;
  const float* P2 = points2 + (size_t)bb * D2_ * S_;   // [256][4096]
  f32x4 acc[4][4];
  f32x4 z = {0.f, 0.f, 0.f, 0.f};
#pragma unroll
  for (int i = 0; i < 4; ++i)
#pragma unroll
    for (int j = 0; j < 4; ++j) acc[i][j] = z;
  int sA = t & 127, kgA = t >> 7;               // A: 128 s x 32 k, 8 k per thread
  int nB = t & 255, kgB = t >> 8;               // B: 256 n x 32 k, 16 k per thread
  for (int k0 = 0; k0 < 256; k0 += 32) {
    __syncthreads();
    {
      bf16x8 ap;
#pragma unroll
      for (int kk = 0; kk < 8; ++kk)
        ap[kk] = (bf16_t)P2[(size_t)(k0 + kgA * 8 + kk) * S_ + m0 + sA];
      *(bf16x8*)&As[sA * LDP + kgA * 8] = ap;
      bf16x8 bp0, bp1;
#pragma unroll
      for (int kk = 0; kk < 8; ++kk) {
        bp0[kk] = (bf16_t)w1[(size_t)(128 + k0 + kgB * 16 + kk) * C1_ + nB];
        bp1[kk] = (bf16_t)w1[(size_t)(128 + k0 + kgB * 16 + 8 + kk) * C1_ + nB];
      }
      *(bf16x8*)&Bs[nB * LDP + kgB * 16] = bp0;
      *(bf16x8*)&Bs[nB * LDP + kgB * 16 + 8] = bp1;
    }
    __syncthreads();
    bf16x8 af[4], bfr[4];
    int arow = wr * 64 + (lane & 15);
    int brow = wc * 64 + (lane & 15);
    int kc = 8 * (lane >> 4);
#pragma unroll
    for (int i = 0; i < 4; ++i) af[i]  = *(const bf16x8*)&As[(arow + i * 16) * LDP + kc];
#pragma unroll
    for (int j = 0; j < 4; ++j) bfr[j] = *(const bf16x8*)&Bs[(brow + j * 16) * LDP + kc];
#pragma unroll
    for (int i = 0; i < 4; ++i)
#pragma unroll
      for (int j = 0; j < 4; ++j)
        acc[i][j] = __builtin_amdgcn_mfma_f32_16x16x32_bf16(af[i], bfr[j], acc[i][j], 0, 0, 0);
  }
  bf16_t* Gb = G + (size_t)bb * S_ * 256;
#pragma unroll
  for (int j = 0; j < 4; ++j) {
    int col = wc * 64 + j * 16 + (lane & 15);
#pragma unroll
    for (int i = 0; i < 4; ++i) {
      int r = m0 + wr * 64 + i * 16 + ((lane >> 4) << 2);
#pragma unroll
      for (int q = 0; q < 4; ++q)
        Gb[(size_t)(r + q) * 256 + col] = (bf16_t)acc[i][j][q];
    }
  }
}

// ---------------------------------------------------------------- K2: GEMM1 [32768x128]@[128x256] BN=256 + b1 + Sum w_j G[i_j] -> y1 bf16, BN stats
// 512 threads, 8 waves 2x4; single n-tile => gather runs ONCE per row.
__global__ __launch_bounds__(512) void gemm1_k(const bf16_t* __restrict__ A,
                                               const bf16_t* __restrict__ Bt,
                                               const float* __restrict__ bias,
                                               const bf16_t* __restrict__ G,
                                               const float* __restrict__ KW,
                                               const int* __restrict__ KI,
                                               bf16_t* __restrict__ Y,
                                               float* __restrict__ st) {
  const int K = 128;
  __shared__ bf16_t As[128 * 32];               // 8KB
  __shared__ bf16_t Bs[256 * 32];               // 16KB
  int tid = threadIdx.x, lane = tid & 63, w = tid >> 6;
  int wr = w >> 2, wc = w & 3;                  // 2x4 waves; wave tile 64m x 64n
  int m0 = blockIdx.x * 128;
  int ra = tid >> 2, ca = (tid & 3) * 8;        // staging coords
  f32x4 acc[4][4];
  f32x4 z = {0.f, 0.f, 0.f, 0.f};
#pragma unroll
  for (int i = 0; i < 4; ++i)
#pragma unroll
    for (int j = 0; j < 4; ++j) acc[i][j] = z;
  for (int k0 = 0; k0 < K; k0 += 32) {
    __syncthreads();
    gload16(A + (size_t)(m0 + ra) * K + k0 + ca, &As[ra * 32 + ca]);
    gload16(Bt + (size_t)ra * K + k0 + ca, &Bs[ra * 32 + ca]);
    gload16(Bt + (size_t)(128 + ra) * K + k0 + ca, &Bs[(128 + ra) * 32 + ca]);
    __syncthreads();
    bf16x8 af[4], bfr[4];
    int arow = wr * 64 + (lane & 15);
    int brow = wc * 64 + (lane & 15);
    int kc = 8 * (lane >> 4);
#pragma unroll
    for (int i = 0; i < 4; ++i) af[i]  = *(const bf16x8*)&As[(arow + i * 16) * 32 + kc];
#pragma unroll
    for (int j = 0; j < 4; ++j) bfr[j] = *(const bf16x8*)&Bs[(brow + j * 16) * 32 + kc];
#pragma unroll
    for (int i = 0; i < 4; ++i)
#pragma unroll
      for (int j = 0; j < 4; ++j)
        acc[i][j] = __builtin_amdgcn_mfma_f32_16x16x32_bf16(af[i], bfr[j], acc[i][j], 0, 0, 0);
  }
  // stage this block's KW/KI into LDS (reuse As)
  __syncthreads();
  float* kwls = (float*)As;                   // 128*3 floats
  int*   kils = ((int*)As) + 384;             // 128*3 ints
  if (tid < 128) {
    int r = m0 + tid;
    kwls[tid * 3 + 0] = KW[(size_t)r * 3 + 0];
    kwls[tid * 3 + 1] = KW[(size_t)r * 3 + 1];
    kwls[tid * 3 + 2] = KW[(size_t)r * 3 + 2];
    kils[tid * 3 + 0] = KI[(size_t)r * 3 + 0];
    kils[tid * 3 + 1] = KI[(size_t)r * 3 + 1];
    kils[tid * 3 + 2] = KI[(size_t)r * 3 + 2];
  }
  __syncthreads();
  int bb = m0 >> 14;
  const bf16_t* Gb = G + (size_t)bb * S_ * 256;
  float sjv[4]  = {0.f, 0.f, 0.f, 0.f};
  float ssjv[4] = {0.f, 0.f, 0.f, 0.f};
#pragma unroll
  for (int i = 0; i < 4; ++i) {
#pragma unroll
    for (int qq = 0; qq < 4; ++qq) {
      int rl = wr * 64 + i * 16 + ((lane >> 4) << 2) + qq;
      float w0 = kwls[rl * 3 + 0], w1v = kwls[rl * 3 + 1], w2v = kwls[rl * 3 + 2];
      const bf16_t* g0 = Gb + (size_t)kils[rl * 3 + 0] * 256;
      const bf16_t* g1 = Gb + (size_t)kils[rl * 3 + 1] * 256;
      const bf16_t* g2 = Gb + (size_t)kils[rl * 3 + 2] * 256;
      int r = m0 + rl;
#pragma unroll
      for (int j = 0; j < 4; ++j) {
        int col = wc * 64 + j * 16 + (lane & 15);
        float y = acc[i][j][qq] + bias[col]
                + w0 * (float)g0[col] + w1v * (float)g1[col] + w2v * (float)g2[col];
        Y[(size_t)r * C1_ + col] = (bf16_t)y;
        sjv[j] += y;  ssjv[j] += y * y;
      }
    }
  }
#pragma unroll
  for (int j = 0; j < 4; ++j) {
    float sj = sjv[j], ssj = ssjv[j];
    sj  += __shfl_xor(sj, 16);  sj  += __shfl_xor(sj, 32);
    ssj += __shfl_xor(ssj, 16); ssj += __shfl_xor(ssj, 32);
    if ((lane >> 4) == 0) {
      int col = wc * 64 + j * 16 + (lane & 15);
      atomicAdd(&st[col], sj);
      atomicAdd(&st[C1_ + col], ssj);
    }
  }
}

// ---------------------------------------------------------------- K3: GEMM2 BM=128 with fused BN1(A-load, prefetched) -> raw y2 transposed + BN2 stats
__global__ __launch_bounds__(256) void gemm2_k(const bf16_t* __restrict__ Y1,
                                               const bf16_t* __restrict__ Bt,
                                               const float* __restrict__ bias,
                                               const float* __restrict__ st1,
                                               const float* __restrict__ g1v,
                                               const float* __restrict__ be1,
                                               float* __restrict__ OUT,
                                               float* __restrict__ st2) {
  const int K = 256;
  __shared__ bf16_t As[128 * 32];
  __shared__ bf16_t Bs[128 * 32];
  __shared__ float sa1[C1_], sb1[C1_];
  int tid = threadIdx.x, lane = tid & 63, w = tid >> 6;
  int wr = w >> 1, wc = w & 1;
  int m0 = blockIdx.x * 128;
  {                                             // BN1 coefficients
    const float invM = 1.f / (float)M_;
    float mu  = st1[tid] * invM;
    float var = fmaxf(st1[C1_ + tid] * invM - mu * mu, 0.f);
    float a = g1v[tid] * rsqrtf(var + 1e-5f);
    sa1[tid] = a;
    sb1[tid] = be1[tid] - mu * a;
  }
  int e0 = (w * 2 + 0) * 512 + lane * 8;
  int e1 = (w * 2 + 1) * 512 + lane * 8;
  int ra0 = e0 >> 5, ca0 = e0 & 31;
  int ra1 = e1 >> 5, ca1 = e1 & 31;
  f32x4 acc[4][4];
  f32x4 z = {0.f, 0.f, 0.f, 0.f};
#pragma unroll
  for (int i = 0; i < 4; ++i)
#pragma unroll
    for (int j = 0; j < 4; ++j) acc[i][j] = z;
  bf16x8 va0 = *(const bf16x8*)&Y1[(size_t)(m0 + ra0) * C1_ + ca0];
  bf16x8 va1 = *(const bf16x8*)&Y1[(size_t)(m0 + ra1) * C1_ + ca1];
  __syncthreads();                              // sa1/sb1 ready
  for (int k0 = 0; k0 < K; k0 += 32) {
    bf16x8 nb0, nb1;
    if (k0 + 32 < K) {                          // 1-deep prefetch
      nb0 = *(const bf16x8*)&Y1[(size_t)(m0 + ra0) * C1_ + k0 + 32 + ca0];
      nb1 = *(const bf16x8*)&Y1[(size_t)(m0 + ra1) * C1_ + k0 + 32 + ca1];
    }
    if (k0) __syncthreads();
    bf16x8 oa0, oa1;
#pragma unroll
    for (int u = 0; u < 8; ++u) {
      float f0 = (float)va0[u];
      float f1 = (float)va1[u];
      f0 = fmaxf(f0 * sa1[k0 + ca0 + u] + sb1[k0 + ca0 + u], 0.f);
      f1 = fmaxf(f1 * sa1[k0 + ca1 + u] + sb1[k0 + ca1 + u], 0.f);
      oa0[u] = (bf16_t)f0;
      oa1[u] = (bf16_t)f1;
    }
    *(bf16x8*)&As[e0] = oa0;
    *(bf16x8*)&As[e1] = oa1;
    gload16(Bt + (size_t)ra0 * K + k0 + ca0, &Bs[e0]);
    gload16(Bt + (size_t)ra1 * K + k0 + ca1, &Bs[e1]);
    __syncthreads();
    bf16x8 af[4], bfr[4];
    int arow = wr * 64 + (lane & 15);
    int brow = wc * 64 + (lane & 15);
    int kc = 8 * (lane >> 4);
#pragma unroll
    for (int i = 0; i < 4; ++i) af[i]  = *(const bf16x8*)&As[(arow + i * 16) * 32 + kc];
#pragma unroll
    for (int j = 0; j < 4; ++j) bfr[j] = *(const bf16x8*)&Bs[(brow + j * 16) * 32 + kc];
#pragma unroll
    for (int i = 0; i < 4; ++i)
#pragma unroll
      for (int j = 0; j < 4; ++j)
        acc[i][j] = __builtin_amdgcn_mfma_f32_16x16x32_bf16(af[i], bfr[j], acc[i][j], 0, 0, 0);
    va0 = nb0; va1 = nb1;
  }
#pragma unroll
  for (int j = 0; j < 4; ++j) {
    int col = wc * 64 + j * 16 + (lane & 15);
    float bv = bias[col];
    float sj = 0.f, ssj = 0.f;
#pragma unroll
    for (int i = 0; i < 4; ++i) {
      int r  = m0 + wr * 64 + i * 16 + ((lane >> 4) << 2);
      int bb = r >> 14, n = r & (N_ - 1);
      f32x4 v = acc[i][j];
#pragma unroll
      for (int q = 0; q < 4; ++q) {
        v[q] += bv;
        sj += v[q]; ssj += v[q] * v[q];
      }
      *(f32x4*)&OUT[((size_t)(bb * C2_ + col)) * N_ + n] = v;
    }
    sj  += __shfl_xor(sj, 16);  sj  += __shfl_xor(sj, 32);
    ssj += __shfl_xor(ssj, 16); ssj += __shfl_xor(ssj, 32);
    if ((lane >> 4) == 0) {
      atomicAdd(&st2[col], sj);
      atomicAdd(&st2[C2_ + col], ssj);
    }
  }
}

// ---------------------------------------------------------------- K4: in-place BN2+ReLU on d_out (BN finalize folded in)
__global__ __launch_bounds__(256) void bn2apply_k(float* __restrict__ OUT,
                                                  const float* __restrict__ st,
                                                  const float* __restrict__ g,
                                                  const float* __restrict__ be) {
  __shared__ float ab[2];
  int t = threadIdx.x;
  int c = (blockIdx.x >> 4) & 127;             // 16 blocks per (b,c) row
  if (t == 0) {
    const float invM = 1.f / (float)M_;
    float mu  = st[c] * invM;
    float var = fmaxf(st[C2_ + c] * invM - mu * mu, 0.f);
    float a = g[c] * rsqrtf(var + 1e-5f);
    ab[0] = a;
    ab[1] = be[c] - mu * a;
  }
  __syncthreads();
  float a = ab[0], s = ab[1];
  size_t i4 = (size_t)blockIdx.x * 256 + t;    // float4 index
  f32x4 v = *(f32x4*)&OUT[i4 * 4];
#pragma unroll
  for (int u = 0; u < 4; ++u) v[u] = fmaxf(a * v[u] + s, 0.f);
  *(f32x4*)&OUT[i4 * 4] = v;
}

// ---------------------------------------------------------------- launch
extern "C" void kernel_launch(void* const* d_in, const int* in_sizes, int n_in,
                              void* d_out, int out_size, void* d_ws, size_t ws_size,
                              hipStream_t stream) {
  const float* xyz1    = (const float*)d_in[0];
  const float* xyz2    = (const float*)d_in[1];
  const float* points1 = (const float*)d_in[2];
  const float* points2 = (const float*)d_in[3];
  const float* w1      = (const float*)d_in[4];
  const float* b1      = (const float*)d_in[5];
  const float* g1      = (const float*)d_in[6];
  const float* beta1   = (const float*)d_in[7];
  const float* w2      = (const float*)d_in[8];
  const float* b2      = (const float*)d_in[9];
  const float* g2      = (const float*)d_in[10];
  const float* beta2   = (const float*)d_in[11];
  float* out = (float*)d_out;

  char* p = (char*)d_ws;
  size_t off = 0;
  bf16_t* Xp1  = (bf16_t*)(p + off); off += (size_t)M_ * 128 * 2;        // 8 MB
  bf16_t* W1AT = (bf16_t*)(p + off); off += (size_t)C1_ * 128 * 2;       // 64 KB
  bf16_t* W2T  = (bf16_t*)(p + off); off += (size_t)C2_ * C1_ * 2;       // 64 KB
  bf16_t* G    = (bf16_t*)(p + off); off += (size_t)B_ * S_ * 256 * 2;   // 4 MB
  bf16_t* Y1   = (bf16_t*)(p + off); off += (size_t)M_ * C1_ * 2;        // 16 MB
  float*  KW   = (float*)(p + off);  off += (size_t)M_ * 3 * 4;          // 384 KB
  int*    KI   = (int*)(p + off);    off += (size_t)M_ * 3 * 4;          // 384 KB
  float*  ST1  = (float*)(p + off);  off += 2048;
  float*  ST2  = (float*)(p + off);  off += 1024;

  hipMemsetAsync(ST1, 0, 3072, stream);   // ST1 + ST2 contiguous

  phase1_k<<<3200, 512, 0, stream>>>(xyz1, xyz2, points1, w1, w2,
                                     KW, KI, Xp1, W1AT, W2T);
  gemmG_k<<<64, 512, 0, stream>>>(points2, w1, G);
  gemm1_k<<<M_ / 128, 512, 0, stream>>>(Xp1, W1AT, b1, G, KW, KI, Y1, ST1);
  gemm2_k<<<M_ / 128, 256, 0, stream>>>(Y1, W2T, b2, ST1, g1, beta1, out, ST2);
  bn2apply_k<<<4096, 256, 0, stream>>>(out, ST2, g2, beta2);
}